// Round 1
// baseline (129.619 us; speedup 1.0000x reference)
//
#include <hip/hip_runtime.h>
#include <hip/hip_bf16.h>

#define NPIX 9216      // H*W
#define NB 2
#define NC 64
#define NJT 576        // NPIX/16
#define JQ 144         // NPIX/64 (j-tiles of 16, 4 per block)
#define STAGE_I 256    // i's staged in LDS per chunk

typedef __attribute__((ext_vector_type(8))) short s16x8;
typedef __attribute__((ext_vector_type(4))) float fp32x4;

__device__ __forceinline__ short bf16b(float f) {
  unsigned u = __builtin_bit_cast(unsigned, f);
  u += 0x7FFFu + ((u >> 16) & 1u);          // RNE, no NaN in this data
  return (short)(u >> 16);
}

// ---------------- Stage 1: per-pixel 1x1 convs -> q,k (bf16 [b][pix][8]) and
// V packed for PV-MFMA B-operand: vbf[b][blk=i/32][ct=c/16][lane=c%16+16*s][t]
// with kappa(s,t): i0 = 4*s + t (t<4), i0 = 16 + 4*s + (t-4) (t>=4).
__global__ __launch_bounds__(256) void cvt_qkv_kernel(
    const float* __restrict__ rv, const float* __restrict__ bev,
    const float* __restrict__ Wq, const float* __restrict__ bq,
    const float* __restrict__ Wk, const float* __restrict__ bk,
    const float* __restrict__ Wv, const float* __restrict__ bv,
    short* __restrict__ qbf, short* __restrict__ kbf, short* __restrict__ vbf)
{
  const int j = blockIdx.x * 256 + threadIdx.x;
  const int b = blockIdx.y;
  const float* xb = bev + (size_t)b * NC * NPIX + j;
  const float* xr = rv  + (size_t)b * NC * NPIX + j;
  float qa[8], ka[8], va[64];
#pragma unroll
  for (int d = 0; d < 8; ++d) { qa[d] = bq[d]; ka[d] = bk[d]; }
#pragma unroll
  for (int o = 0; o < 64; ++o) va[o] = bv[o];
  for (int c = 0; c < 64; ++c) {
    float bx = xb[(size_t)c * NPIX];
    float rx = xr[(size_t)c * NPIX];
#pragma unroll
    for (int d = 0; d < 8; ++d) {
      qa[d] = fmaf(Wq[d * 64 + c], bx, qa[d]);
      ka[d] = fmaf(Wk[d * 64 + c], rx, ka[d]);
    }
#pragma unroll
    for (int o = 0; o < 64; ++o) va[o] = fmaf(Wv[o * 64 + c], rx, va[o]);
  }
  s16x8 qp, kp;
#pragma unroll
  for (int d = 0; d < 8; ++d) { qp[d] = bf16b(qa[d]); kp[d] = bf16b(ka[d]); }
  ((s16x8*)qbf)[(size_t)b * NPIX + j] = qp;
  ((s16x8*)kbf)[(size_t)b * NPIX + j] = kp;
  const int blk = j >> 5, i0 = j & 31;
  const int s = (i0 >> 2) & 3;
  const int t = (i0 & 3) + 4 * (i0 >> 4);
#pragma unroll
  for (int c = 0; c < 64; ++c) {
    int ct = c >> 4, cp = c & 15;
    vbf[((((size_t)b * 288 + blk) * 4 + ct) * 64 + cp + 16 * s) * 8 + t] = bf16b(va[c]);
  }
}

// ---------------- Stage 2: flash attention (i-split into nic chunks).
// Block = 4 waves, wave w owns j-tile jt = (bid%JQ)*4+w (16 j's).
// Per i32-block: S = mfma(A=Qfrag, B=Kfrag) twice (D=8 padded in K=32);
// lane-local exp+pack -> PV A-frag; 4 PV MFMAs over c-tiles.
__global__ __launch_bounds__(256) void attn_kernel(
    const short* __restrict__ qbf, const short* __restrict__ kbf,
    const short* __restrict__ vbf,
    float* __restrict__ numws, float* __restrict__ denws, int nic)
{
  __shared__ short lds_v[8 * 4 * 64 * 8];   // 32 KB: [blk8][ct4][lane64][t8]
  __shared__ short lds_q[STAGE_I * 8];      // 4 KB
  const int bid = blockIdx.x;
  const int jq = bid % JQ;
  const int rest = bid / JQ;
  const int b = rest % NB;
  const int ic = rest / NB;
  const int tid = threadIdx.x;
  const int wid = tid >> 6, lane = tid & 63;
  const int jt = jq * 4 + wid;
  const int jbase = jt * 16;
  const int ichunk = NPIX / nic;
  const int ibase = ic * ichunk;
  const int nchunks = ichunk / STAGE_I;

  const s16x8* q8 = (const s16x8*)qbf;
  const s16x8* k8 = (const s16x8*)kbf;
  const s16x8* v8 = (const s16x8*)vbf;
  s16x8* lv8 = (s16x8*)lds_v;
  s16x8* lq8 = (s16x8*)lds_q;

  const s16x8 zS = {0, 0, 0, 0, 0, 0, 0, 0};
  const fp32x4 z4 = {0.f, 0.f, 0.f, 0.f};

  // K fragment (B-operand of score MFMA): lanes 0-15 hold k[d=0..7, jbase+lane].
  // Lanes 16-63 must be finite (A is zero there) -> zero them.
  s16x8 kf = zS;
  if (lane < 16) kf = k8[(size_t)b * NPIX + jbase + lane];

  fp32x4 acc0 = z4, acc1 = z4, acc2 = z4, acc3 = z4;
  float den = 0.f;

  for (int ch = 0; ch < nchunks; ++ch) {
    const int cbase = ibase + ch * STAGE_I;
    {
      const size_t vsrc = ((size_t)b * 288 + (cbase >> 5)) * 256;
#pragma unroll
      for (int r = 0; r < 8; ++r) lv8[r * 256 + tid] = v8[vsrc + r * 256 + tid];
      lq8[tid] = q8[(size_t)b * NPIX + cbase + tid];
    }
    __syncthreads();
#pragma unroll
    for (int it = 0; it < 8; ++it) {
      // Q fragments (A-operand): lanes 0-15 real, lanes 16-63 MUST be zero.
      s16x8 q0 = lq8[it * 32 + (lane & 15)];
      s16x8 q1 = lq8[it * 32 + 16 + (lane & 15)];
      if (lane >= 16) { q0 = zS; q1 = zS; }
      fp32x4 s1 = __builtin_amdgcn_mfma_f32_16x16x32_bf16(q0, kf, z4, 0, 0, 0);
      fp32x4 s2 = __builtin_amdgcn_mfma_f32_16x16x32_bf16(q1, kf, z4, 0, 0, 0);
      // lane holds S[i0 = 4*(lane>>4)+r (+16 for s2), j' = lane&15]
      float e0 = __expf(s1[0]), e1 = __expf(s1[1]), e2 = __expf(s1[2]), e3 = __expf(s1[3]);
      float e4 = __expf(s2[0]), e5 = __expf(s2[1]), e6 = __expf(s2[2]), e7 = __expf(s2[3]);
      den += (e0 + e1) + (e2 + e3) + ((e4 + e5) + (e6 + e7));
      s16x8 pa;
      pa[0] = bf16b(e0); pa[1] = bf16b(e1); pa[2] = bf16b(e2); pa[3] = bf16b(e3);
      pa[4] = bf16b(e4); pa[5] = bf16b(e5); pa[6] = bf16b(e6); pa[7] = bf16b(e7);
      s16x8 v0 = lv8[(it * 4 + 0) * 64 + lane];
      s16x8 v1 = lv8[(it * 4 + 1) * 64 + lane];
      s16x8 v2 = lv8[(it * 4 + 2) * 64 + lane];
      s16x8 v3 = lv8[(it * 4 + 3) * 64 + lane];
      acc0 = __builtin_amdgcn_mfma_f32_16x16x32_bf16(pa, v0, acc0, 0, 0, 0);
      acc1 = __builtin_amdgcn_mfma_f32_16x16x32_bf16(pa, v1, acc1, 0, 0, 0);
      acc2 = __builtin_amdgcn_mfma_f32_16x16x32_bf16(pa, v2, acc2, 0, 0, 0);
      acc3 = __builtin_amdgcn_mfma_f32_16x16x32_bf16(pa, v3, acc3, 0, 0, 0);
    }
    __syncthreads();
  }
  // den per lane is partial for column j' = lane&15; reduce across the 4 s-groups
  den += __shfl_xor(den, 16);
  den += __shfl_xor(den, 32);
  const size_t base = (size_t)(ic * NB + b) * NJT + jt;
  if (lane < 16) denws[base * 16 + lane] = den;
  fp32x4* nw = (fp32x4*)numws;
  nw[(base * 4 + 0) * 64 + lane] = acc0;
  nw[(base * 4 + 1) * 64 + lane] = acc1;
  nw[(base * 4 + 2) * 64 + lane] = acc2;
  nw[(base * 4 + 3) * 64 + lane] = acc3;
}

// ---------------- Stage 3: combine i-splits, normalize, add residual.
__global__ __launch_bounds__(256) void combine_kernel(
    const float* __restrict__ bev, const float* __restrict__ numws,
    const float* __restrict__ denws, float* __restrict__ out, int nic)
{
  const int j = blockIdx.x * 256 + threadIdx.x;
  const int c = blockIdx.y;
  const int b = blockIdx.z;
  const int jt = j >> 4, jp = j & 15;
  const int lane = (c & 15) + 16 * (jp >> 2);
  const int r = j & 3, ct = c >> 4;
  float dsum = 0.f, nsum = 0.f;
  for (int ic = 0; ic < nic; ++ic) {
    const size_t base = (size_t)(ic * NB + b) * NJT + jt;
    dsum += denws[base * 16 + jp];
    nsum += numws[((base * 4 + ct) * 64 + lane) * 4 + r];
  }
  const size_t o = ((size_t)b * NC + c) * NPIX + j;
  out[o] = bev[o] + nsum / dsum;
}

extern "C" void kernel_launch(void* const* d_in, const int* in_sizes, int n_in,
                              void* d_out, int out_size, void* d_ws, size_t ws_size,
                              hipStream_t stream) {
  const float* rv  = (const float*)d_in[0];
  const float* bev = (const float*)d_in[1];
  const float* Wq  = (const float*)d_in[2];
  const float* bq  = (const float*)d_in[3];
  const float* Wk  = (const float*)d_in[4];
  const float* bk  = (const float*)d_in[5];
  const float* Wv  = (const float*)d_in[6];
  const float* bv  = (const float*)d_in[7];
  float* out = (float*)d_out;

  short* qbf = (short*)d_ws;
  short* kbf = qbf + (size_t)NB * NPIX * 8;
  short* vbf = kbf + (size_t)NB * NPIX * 8;
  float* denws = (float*)(vbf + (size_t)NB * NPIX * 64);

  const size_t fixed = (size_t)NB * NPIX * (8 + 8 + 64) * 2;  // qkv bytes
  int nic = 4;
  while (nic > 1) {
    size_t need = fixed + (size_t)nic * NB * NJT * 16 * 4
                        + (size_t)nic * NB * NJT * 4 * 64 * 4 * 4;
    if (need <= ws_size) break;
    nic >>= 1;
  }
  float* numws = denws + (size_t)nic * NB * NJT * 16;

  cvt_qkv_kernel<<<dim3(NPIX / 256, NB), 256, 0, stream>>>(
      rv, bev, Wq, bq, Wk, bk, Wv, bv, qbf, kbf, vbf);
  attn_kernel<<<dim3(nic * NB * JQ), 256, 0, stream>>>(
      qbf, kbf, vbf, numws, denws, nic);
  combine_kernel<<<dim3(NPIX / 256, NC, NB), 256, 0, stream>>>(
      bev, numws, denws, out, nic);
}

// Round 2
// 109.904 us; speedup vs baseline: 1.1794x; 1.1794x over previous
//
#include <hip/hip_runtime.h>
#include <hip/hip_bf16.h>

#define NPIX 9216      // H*W
#define NB 2
#define NC 64
#define NJT 576        // NPIX/16  (16-j tiles per (b,ic))
#define JQ 144         // NPIX/64  (64-j blocks)
#define STAGE_I 128    // i's staged in LDS per chunk

typedef __attribute__((ext_vector_type(8))) short s16x8;
typedef __attribute__((ext_vector_type(4))) float fp32x4;

#define LOG2E 1.44269504088896340736f

#if defined(__has_builtin)
#if __has_builtin(__builtin_amdgcn_exp2f)
#define EXP2(x) __builtin_amdgcn_exp2f(x)
#endif
#endif
#ifndef EXP2
#define EXP2(x) exp2f(x)
#endif

__device__ __forceinline__ short bf16b(float f) {
  unsigned u = __builtin_bit_cast(unsigned, f);
  u += 0x7FFFu + ((u >> 16) & 1u);          // RNE, no NaN in this data
  return (short)(u >> 16);
}

__device__ __forceinline__ int cvtpk(float a, float b) {
  int r;
  asm("v_cvt_pk_bf16_f32 %0, %1, %2" : "=v"(r) : "v"(a), "v"(b));
  return r;
}

// ---------------- Stage 1: per-pixel 1x1 convs -> q (pre-scaled by log2e), k
// (bf16 [b][pix][8]) and V packed for the PV-MFMA B-operand:
// vbf[b][blk=i/32][ct=c/16][lane=c%16+16*s][t], i0 = 4s+t (t<4), 16+4s+(t-4).
// Block = 256 threads = 64 j x 4 channel-groups; weights staged in LDS.
__global__ __launch_bounds__(256) void cvt_qkv_kernel(
    const float* __restrict__ rv, const float* __restrict__ bev,
    const float* __restrict__ Wq, const float* __restrict__ bq,
    const float* __restrict__ Wk, const float* __restrict__ bk,
    const float* __restrict__ Wv, const float* __restrict__ bv,
    short* __restrict__ qbf, short* __restrict__ kbf, short* __restrict__ vbf)
{
  __shared__ float wlds[5120];       // Wv [64][64] @0, Wq*log2e [8][64] @4096, Wk [8][64] @4608
  __shared__ short vlds[64][72];     // v transpose buffer [c][j] (+pad)
  const int tid = threadIdx.x;
  const int jb = blockIdx.x, b = blockIdx.y;
  const int jbase = jb * 64;

  for (int idx = tid; idx < 4096; idx += 256) wlds[idx] = Wv[idx];
  {
    int idx = tid;
#pragma unroll
    for (int r = 0; r < 4; ++r, idx += 256)
      wlds[4096 + idx] = (idx < 512) ? Wq[idx] * LOG2E : Wk[idx - 512];
  }
  __syncthreads();

  const int jl = tid & 63, cg = tid >> 6;
  const float* xr = rv  + (size_t)b * NC * NPIX + jbase + jl;
  const float* xb = bev + (size_t)b * NC * NPIX + jbase + jl;

  float va[16];
#pragma unroll
  for (int u = 0; u < 16; ++u) va[u] = bv[cg * 16 + u];
  float qk[8];
  if (cg == 0) {
#pragma unroll
    for (int u = 0; u < 8; ++u) qk[u] = bq[u] * LOG2E;
  } else if (cg == 1) {
#pragma unroll
    for (int u = 0; u < 8; ++u) qk[u] = bk[u];
  }

  for (int c2 = 0; c2 < 32; ++c2) {
    const int c = c2 * 2;
    const float x0 = xr[(size_t)c * NPIX], x1 = xr[(size_t)(c + 1) * NPIX];
#pragma unroll
    for (int u = 0; u < 16; ++u) {
      float2 w = *(const float2*)&wlds[(cg * 16 + u) * 64 + c];
      va[u] = fmaf(w.y, x1, fmaf(w.x, x0, va[u]));
    }
    if (cg == 0) {
      const float y0 = xb[(size_t)c * NPIX], y1 = xb[(size_t)(c + 1) * NPIX];
#pragma unroll
      for (int u = 0; u < 8; ++u) {
        float2 w = *(const float2*)&wlds[4096 + u * 64 + c];
        qk[u] = fmaf(w.y, y1, fmaf(w.x, y0, qk[u]));
      }
    } else if (cg == 1) {
#pragma unroll
      for (int u = 0; u < 8; ++u) {
        float2 w = *(const float2*)&wlds[4608 + u * 64 + c];
        qk[u] = fmaf(w.y, x1, fmaf(w.x, x0, qk[u]));
      }
    }
  }

  if (cg == 0) {
    s16x8 qp;
#pragma unroll
    for (int u = 0; u < 8; ++u) qp[u] = bf16b(qk[u]);
    ((s16x8*)qbf)[(size_t)b * NPIX + jbase + jl] = qp;
  } else if (cg == 1) {
    s16x8 kp;
#pragma unroll
    for (int u = 0; u < 8; ++u) kp[u] = bf16b(qk[u]);
    ((s16x8*)kbf)[(size_t)b * NPIX + jbase + jl] = kp;
  }
#pragma unroll
  for (int u = 0; u < 16; ++u) vlds[cg * 16 + u][jl] = bf16b(va[u]);
  __syncthreads();

  s16x8* vout = (s16x8*)vbf + ((size_t)b * 288 + jb * 2) * 256;
#pragma unroll
  for (int r = 0; r < 2; ++r) {
    const int vecidx = r * 256 + tid;
    const int ct = (vecidx >> 6) & 3, ln = vecidx & 63;
    const int s = ln >> 4, cc = ct * 16 + (ln & 15);
    s16x8 vv;
#pragma unroll
    for (int t = 0; t < 8; ++t) {
      const int i0 = (t < 4) ? (4 * s + t) : (12 + 4 * s + t);
      vv[t] = vlds[cc][r * 32 + i0];
    }
    vout[vecidx] = vv;
  }
}

// ---------------- Stage 2: flash attention. Block = 128 threads = 2 waves.
// Each wave owns TWO 16-j tiles (32 j) so every V fragment read from LDS
// feeds 2x the MFMA work. Scores arrive pre-scaled by log2e -> exp2 direct.
// Denominator via an extra MFMA against a ones-column B fragment.
__global__ __launch_bounds__(128) void attn_kernel(
    const short* __restrict__ qbf, const short* __restrict__ kbf,
    const short* __restrict__ vbf,
    float* __restrict__ numws, float* __restrict__ denws, int nic)
{
  __shared__ s16x8 lv8[1024];   // 16 KB: [blk4][ct4][lane64]
  __shared__ s16x8 lq8[129];    // slot 128 = zeros (A-operand zero rows)
  const int bid = blockIdx.x;
  const int jq = bid % JQ;
  const int rest = bid / JQ;
  const int b = rest % NB;
  const int ic = rest / NB;
  const int tid = threadIdx.x;        // 0..127
  const int wid = tid >> 6, lane = tid & 63, l15 = lane & 15;
  const int jt0 = jq * 4 + wid * 2, jt1 = jt0 + 1;
  const int ichunk = NPIX / nic;
  const int ibase = ic * ichunk;
  const int nchunks = ichunk / STAGE_I;

  const s16x8* q8 = (const s16x8*)qbf;
  const s16x8* k8 = (const s16x8*)kbf;
  const s16x8* v8 = (const s16x8*)vbf;

  const s16x8 zS = {0, 0, 0, 0, 0, 0, 0, 0};
  const fp32x4 z4 = {0.f, 0.f, 0.f, 0.f};

  s16x8 kf0 = zS, kf1 = zS, onesB = zS;
  if (lane < 16) {
    kf0 = k8[(size_t)b * NPIX + jt0 * 16 + lane];
    kf1 = k8[(size_t)b * NPIX + jt1 * 16 + lane];
  }
  if (l15 == 0) {
    const short one = 0x3F80;  // bf16 1.0
#pragma unroll
    for (int t = 0; t < 8; ++t) onesB[t] = one;
  }

  fp32x4 accA[4] = {z4, z4, z4, z4}, accB[4] = {z4, z4, z4, z4};
  fp32x4 accdA = z4, accdB = z4;
  if (tid == 0) lq8[128] = zS;

  for (int ch = 0; ch < nchunks; ++ch) {
    const int cbase = ibase + ch * STAGE_I;
    const size_t vsrc = ((size_t)b * 288 + (cbase >> 5)) * 256;
#pragma unroll
    for (int r = 0; r < 8; ++r) lv8[r * 128 + tid] = v8[vsrc + r * 128 + tid];
    lq8[tid] = q8[(size_t)b * NPIX + cbase + tid];
    __syncthreads();
#pragma unroll
    for (int it = 0; it < 4; ++it) {
      int qi0 = it * 32 + l15, qi1 = qi0 + 16;
      if (lane >= 16) { qi0 = 128; qi1 = 128; }
      const s16x8 q0 = lq8[qi0], q1 = lq8[qi1];
      const fp32x4 sA0 = __builtin_amdgcn_mfma_f32_16x16x32_bf16(q0, kf0, z4, 0, 0, 0);
      const fp32x4 sA1 = __builtin_amdgcn_mfma_f32_16x16x32_bf16(q1, kf0, z4, 0, 0, 0);
      const fp32x4 sB0 = __builtin_amdgcn_mfma_f32_16x16x32_bf16(q0, kf1, z4, 0, 0, 0);
      const fp32x4 sB1 = __builtin_amdgcn_mfma_f32_16x16x32_bf16(q1, kf1, z4, 0, 0, 0);
      int4 piA, piB;
      piA.x = cvtpk(EXP2(sA0[0]), EXP2(sA0[1]));
      piA.y = cvtpk(EXP2(sA0[2]), EXP2(sA0[3]));
      piA.z = cvtpk(EXP2(sA1[0]), EXP2(sA1[1]));
      piA.w = cvtpk(EXP2(sA1[2]), EXP2(sA1[3]));
      piB.x = cvtpk(EXP2(sB0[0]), EXP2(sB0[1]));
      piB.y = cvtpk(EXP2(sB0[2]), EXP2(sB0[3]));
      piB.z = cvtpk(EXP2(sB1[0]), EXP2(sB1[1]));
      piB.w = cvtpk(EXP2(sB1[2]), EXP2(sB1[3]));
      const s16x8 paA = __builtin_bit_cast(s16x8, piA);
      const s16x8 paB = __builtin_bit_cast(s16x8, piB);
      const s16x8 v0 = lv8[(it * 4 + 0) * 64 + lane];
      const s16x8 v1 = lv8[(it * 4 + 1) * 64 + lane];
      const s16x8 v2 = lv8[(it * 4 + 2) * 64 + lane];
      const s16x8 v3 = lv8[(it * 4 + 3) * 64 + lane];
      accA[0] = __builtin_amdgcn_mfma_f32_16x16x32_bf16(paA, v0, accA[0], 0, 0, 0);
      accA[1] = __builtin_amdgcn_mfma_f32_16x16x32_bf16(paA, v1, accA[1], 0, 0, 0);
      accA[2] = __builtin_amdgcn_mfma_f32_16x16x32_bf16(paA, v2, accA[2], 0, 0, 0);
      accA[3] = __builtin_amdgcn_mfma_f32_16x16x32_bf16(paA, v3, accA[3], 0, 0, 0);
      accB[0] = __builtin_amdgcn_mfma_f32_16x16x32_bf16(paB, v0, accB[0], 0, 0, 0);
      accB[1] = __builtin_amdgcn_mfma_f32_16x16x32_bf16(paB, v1, accB[1], 0, 0, 0);
      accB[2] = __builtin_amdgcn_mfma_f32_16x16x32_bf16(paB, v2, accB[2], 0, 0, 0);
      accB[3] = __builtin_amdgcn_mfma_f32_16x16x32_bf16(paB, v3, accB[3], 0, 0, 0);
      accdA = __builtin_amdgcn_mfma_f32_16x16x32_bf16(paA, onesB, accdA, 0, 0, 0);
      accdB = __builtin_amdgcn_mfma_f32_16x16x32_bf16(paB, onesB, accdB, 0, 0, 0);
    }
    __syncthreads();
  }
  const size_t base0 = (size_t)(ic * NB + b) * NJT + jt0;
  const size_t base1 = base0 + 1;
  if (l15 == 0) {
    fp32x4* dw = (fp32x4*)denws;
    dw[base0 * 4 + (lane >> 4)] = accdA;
    dw[base1 * 4 + (lane >> 4)] = accdB;
  }
  fp32x4* nw = (fp32x4*)numws;
#pragma unroll
  for (int ct = 0; ct < 4; ++ct) {
    nw[(base0 * 4 + ct) * 64 + lane] = accA[ct];
    nw[(base1 * 4 + ct) * 64 + lane] = accB[ct];
  }
}

// ---------------- Stage 3: combine i-splits, normalize, add residual.
__global__ __launch_bounds__(256) void combine_kernel(
    const float* __restrict__ bev, const float* __restrict__ numws,
    const float* __restrict__ denws, float* __restrict__ out, int nic)
{
  const int j = blockIdx.x * 256 + threadIdx.x;
  const int c = blockIdx.y;
  const int b = blockIdx.z;
  const int jt = j >> 4, jp = j & 15;
  const int lane = (c & 15) + 16 * (jp >> 2);
  const int r = j & 3, ct = c >> 4;
  float dsum = 0.f, nsum = 0.f;
  for (int ic = 0; ic < nic; ++ic) {
    const size_t base = (size_t)(ic * NB + b) * NJT + jt;
    dsum += denws[base * 16 + jp];
    nsum += numws[((base * 4 + ct) * 64 + lane) * 4 + r];
  }
  const size_t o = ((size_t)b * NC + c) * NPIX + j;
  out[o] = bev[o] + nsum / dsum;
}

extern "C" void kernel_launch(void* const* d_in, const int* in_sizes, int n_in,
                              void* d_out, int out_size, void* d_ws, size_t ws_size,
                              hipStream_t stream) {
  const float* rv  = (const float*)d_in[0];
  const float* bev = (const float*)d_in[1];
  const float* Wq  = (const float*)d_in[2];
  const float* bq  = (const float*)d_in[3];
  const float* Wk  = (const float*)d_in[4];
  const float* bk  = (const float*)d_in[5];
  const float* Wv  = (const float*)d_in[6];
  const float* bv  = (const float*)d_in[7];
  float* out = (float*)d_out;

  short* qbf = (short*)d_ws;
  short* kbf = qbf + (size_t)NB * NPIX * 8;
  short* vbf = kbf + (size_t)NB * NPIX * 8;
  float* denws = (float*)(vbf + (size_t)NB * NPIX * 64);

  const size_t fixed = (size_t)NB * NPIX * (8 + 8 + 64) * 2;  // qkv bytes
  int nic = 4;
  while (nic > 1) {
    size_t need = fixed + (size_t)nic * NB * NJT * 16 * 4
                        + (size_t)nic * NB * NJT * 4 * 64 * 4 * 4;
    if (need <= ws_size) break;
    nic >>= 1;
  }
  float* numws = denws + (size_t)nic * NB * NJT * 16;

  cvt_qkv_kernel<<<dim3(JQ, NB), 256, 0, stream>>>(
      rv, bev, Wq, bq, Wk, bk, Wv, bv, qbf, kbf, vbf);
  attn_kernel<<<dim3(nic * NB * JQ), 128, 0, stream>>>(
      qbf, kbf, vbf, numws, denws, nic);
  combine_kernel<<<dim3(NPIX / 256, NC, NB), 256, 0, stream>>>(
      bev, numws, denws, out, nic);
}

// Round 3
// 81.931 us; speedup vs baseline: 1.5820x; 1.3414x over previous
//
#include <hip/hip_runtime.h>
#include <hip/hip_bf16.h>

#define NPIX 9216      // H*W
#define NB 2
#define NC 64
#define NJT 576        // NPIX/16  (16-j tiles per (b,ic))
#define JQ 144         // NPIX/64  (64-j blocks)
#define STAGE_I 128    // i's staged in LDS per chunk

typedef __attribute__((ext_vector_type(8))) short s16x8;
typedef __attribute__((ext_vector_type(4))) float fp32x4;

#define LOG2E 1.44269504088896340736f

#if defined(__has_builtin)
#if __has_builtin(__builtin_amdgcn_exp2f)
#define EXP2(x) __builtin_amdgcn_exp2f(x)
#endif
#endif
#ifndef EXP2
#define EXP2(x) exp2f(x)
#endif

__device__ __forceinline__ short bf16b(float f) {
  unsigned u = __builtin_bit_cast(unsigned, f);
  u += 0x7FFFu + ((u >> 16) & 1u);          // RNE, no NaN in this data
  return (short)(u >> 16);
}

__device__ __forceinline__ int cvtpk(float a, float b) {
  int r;
  asm("v_cvt_pk_bf16_f32 %0, %1, %2" : "=v"(r) : "v"(a), "v"(b));
  return r;
}

// ---------------- Stage 1: per-pixel 1x1 convs -> q (pre-scaled by log2e), k
// (bf16 [b][pix][8]) and V packed for the PV-MFMA B-operand:
// vbf[b][blk=i/32][ct=c/16][lane=c%16+16*s][t], i0 = 4s+t (t<4), 16+4s+(t-4).
__global__ __launch_bounds__(256) void cvt_qkv_kernel(
    const float* __restrict__ rv, const float* __restrict__ bev,
    const float* __restrict__ Wq, const float* __restrict__ bq,
    const float* __restrict__ Wk, const float* __restrict__ bk,
    const float* __restrict__ Wv, const float* __restrict__ bv,
    short* __restrict__ qbf, short* __restrict__ kbf, short* __restrict__ vbf)
{
  __shared__ float wlds[5120];       // Wv [64][64] @0, Wq*log2e [8][64] @4096, Wk [8][64] @4608
  __shared__ short vlds[64][72];     // v transpose buffer [c][j] (+pad)
  const int tid = threadIdx.x;
  const int jb = blockIdx.x, b = blockIdx.y;
  const int jbase = jb * 64;

  for (int idx = tid; idx < 4096; idx += 256) wlds[idx] = Wv[idx];
  {
    int idx = tid;
#pragma unroll
    for (int r = 0; r < 4; ++r, idx += 256)
      wlds[4096 + idx] = (idx < 512) ? Wq[idx] * LOG2E : Wk[idx - 512];
  }
  __syncthreads();

  const int jl = tid & 63, cg = tid >> 6;
  const float* xr = rv  + (size_t)b * NC * NPIX + jbase + jl;
  const float* xb = bev + (size_t)b * NC * NPIX + jbase + jl;

  float va[16];
#pragma unroll
  for (int u = 0; u < 16; ++u) va[u] = bv[cg * 16 + u];
  float qk[8];
  if (cg == 0) {
#pragma unroll
    for (int u = 0; u < 8; ++u) qk[u] = bq[u] * LOG2E;
  } else if (cg == 1) {
#pragma unroll
    for (int u = 0; u < 8; ++u) qk[u] = bk[u];
  }

  for (int c2 = 0; c2 < 32; ++c2) {
    const int c = c2 * 2;
    const float x0 = xr[(size_t)c * NPIX], x1 = xr[(size_t)(c + 1) * NPIX];
#pragma unroll
    for (int u = 0; u < 16; ++u) {
      float2 w = *(const float2*)&wlds[(cg * 16 + u) * 64 + c];
      va[u] = fmaf(w.y, x1, fmaf(w.x, x0, va[u]));
    }
    if (cg == 0) {
      const float y0 = xb[(size_t)c * NPIX], y1 = xb[(size_t)(c + 1) * NPIX];
#pragma unroll
      for (int u = 0; u < 8; ++u) {
        float2 w = *(const float2*)&wlds[4096 + u * 64 + c];
        qk[u] = fmaf(w.y, y1, fmaf(w.x, y0, qk[u]));
      }
    } else if (cg == 1) {
#pragma unroll
      for (int u = 0; u < 8; ++u) {
        float2 w = *(const float2*)&wlds[4608 + u * 64 + c];
        qk[u] = fmaf(w.y, x1, fmaf(w.x, x0, qk[u]));
      }
    }
  }

  if (cg == 0) {
    s16x8 qp;
#pragma unroll
    for (int u = 0; u < 8; ++u) qp[u] = bf16b(qk[u]);
    ((s16x8*)qbf)[(size_t)b * NPIX + jbase + jl] = qp;
  } else if (cg == 1) {
    s16x8 kp;
#pragma unroll
    for (int u = 0; u < 8; ++u) kp[u] = bf16b(qk[u]);
    ((s16x8*)kbf)[(size_t)b * NPIX + jbase + jl] = kp;
  }
#pragma unroll
  for (int u = 0; u < 16; ++u) vlds[cg * 16 + u][jl] = bf16b(va[u]);
  __syncthreads();

  s16x8* vout = (s16x8*)vbf + ((size_t)b * 288 + jb * 2) * 256;
#pragma unroll
  for (int r = 0; r < 2; ++r) {
    const int vecidx = r * 256 + tid;
    const int ct = (vecidx >> 6) & 3, ln = vecidx & 63;
    const int s = ln >> 4, cc = ct * 16 + (ln & 15);
    s16x8 vv;
#pragma unroll
    for (int t = 0; t < 8; ++t) {
      const int i0 = (t < 4) ? (4 * s + t) : (12 + 4 * s + t);
      vv[t] = vlds[cc][r * 32 + i0];
    }
    vout[vecidx] = vv;
  }
}

// ---------------- Stage 2: flash attention. Block = 256 threads = 4 waves over
// 64 j's: wave = (ig = wid>>1, jw = wid&1). Waves with ig=0 compute sub-tiles
// it={0,1}, ig=1 compute it={2,3} of every staged 128-i chunk (in-block i-split
// doubles resident waves -> hides MFMA/exp2/LDS latency). Partial accumulators
// merged once at the end via an LDS reduction (reuses staging buffer).
// numws layout: [icb][c][NPIX] (float), denws: [icb][NPIX] -> coalesced combine.
__global__ __launch_bounds__(256, 4) void attn_kernel(
    const short* __restrict__ qbf, const short* __restrict__ kbf,
    const short* __restrict__ vbf,
    float* __restrict__ numws, float* __restrict__ denws, int nic)
{
  __shared__ __align__(16) char smem[20608];
  s16x8* lv8 = (s16x8*)smem;            // [1024] 16 KB: [blk4][ct4][lane64]
  s16x8* lq8 = (s16x8*)(smem + 16384);  // [129], slot 128 = zeros
  fp32x4* red = (fp32x4*)smem;          // [10][128] after the loop (aliases ok)

  const int bid = blockIdx.x;
  const int jq = bid % JQ;
  const int rest = bid / JQ;
  const int b = rest % NB;
  const int ic = rest / NB;
  const int tid = threadIdx.x;        // 0..255
  const int wid = tid >> 6, lane = tid & 63, l15 = lane & 15;
  const int jw = wid & 1;             // which j-pair of the block's 64 j
  const int ig = wid >> 1;            // it-group: 0 -> it 0,1 ; 1 -> it 2,3
  const int jt0 = jq * 4 + jw * 2, jt1 = jt0 + 1;
  const int ichunk = NPIX / nic;
  const int ibase = ic * ichunk;
  const int nchunks = ichunk / STAGE_I;

  const s16x8* q8 = (const s16x8*)qbf;
  const s16x8* k8 = (const s16x8*)kbf;
  const s16x8* v8 = (const s16x8*)vbf;

  const s16x8 zS = {0, 0, 0, 0, 0, 0, 0, 0};
  const fp32x4 z4 = {0.f, 0.f, 0.f, 0.f};

  s16x8 kf0 = zS, kf1 = zS, onesB = zS;
  if (lane < 16) {
    kf0 = k8[(size_t)b * NPIX + jt0 * 16 + lane];
    kf1 = k8[(size_t)b * NPIX + jt1 * 16 + lane];
  }
  if (l15 == 0) {
    const short one = 0x3F80;  // bf16 1.0
#pragma unroll
    for (int t = 0; t < 8; ++t) onesB[t] = one;
  }

  fp32x4 accA[4] = {z4, z4, z4, z4}, accB[4] = {z4, z4, z4, z4};
  fp32x4 accdA = z4, accdB = z4;
  if (tid == 0) lq8[128] = zS;

  for (int ch = 0; ch < nchunks; ++ch) {
    const int cbase = ibase + ch * STAGE_I;
    const size_t vsrc = ((size_t)b * 288 + (cbase >> 5)) * 256;
#pragma unroll
    for (int r = 0; r < 4; ++r) lv8[r * 256 + tid] = v8[vsrc + r * 256 + tid];
    if (tid < 128) lq8[tid] = q8[(size_t)b * NPIX + cbase + tid];
    __syncthreads();
#pragma unroll
    for (int itl = 0; itl < 2; ++itl) {
      const int it = ig * 2 + itl;
      int qi0 = it * 32 + l15, qi1 = qi0 + 16;
      if (lane >= 16) { qi0 = 128; qi1 = 128; }
      const s16x8 q0 = lq8[qi0], q1 = lq8[qi1];
      const fp32x4 sA0 = __builtin_amdgcn_mfma_f32_16x16x32_bf16(q0, kf0, z4, 0, 0, 0);
      const fp32x4 sA1 = __builtin_amdgcn_mfma_f32_16x16x32_bf16(q1, kf0, z4, 0, 0, 0);
      const fp32x4 sB0 = __builtin_amdgcn_mfma_f32_16x16x32_bf16(q0, kf1, z4, 0, 0, 0);
      const fp32x4 sB1 = __builtin_amdgcn_mfma_f32_16x16x32_bf16(q1, kf1, z4, 0, 0, 0);
      int4 piA, piB;
      piA.x = cvtpk(EXP2(sA0[0]), EXP2(sA0[1]));
      piA.y = cvtpk(EXP2(sA0[2]), EXP2(sA0[3]));
      piA.z = cvtpk(EXP2(sA1[0]), EXP2(sA1[1]));
      piA.w = cvtpk(EXP2(sA1[2]), EXP2(sA1[3]));
      piB.x = cvtpk(EXP2(sB0[0]), EXP2(sB0[1]));
      piB.y = cvtpk(EXP2(sB0[2]), EXP2(sB0[3]));
      piB.z = cvtpk(EXP2(sB1[0]), EXP2(sB1[1]));
      piB.w = cvtpk(EXP2(sB1[2]), EXP2(sB1[3]));
      const s16x8 paA = __builtin_bit_cast(s16x8, piA);
      const s16x8 paB = __builtin_bit_cast(s16x8, piB);
      const s16x8 v0 = lv8[(it * 4 + 0) * 64 + lane];
      const s16x8 v1 = lv8[(it * 4 + 1) * 64 + lane];
      const s16x8 v2 = lv8[(it * 4 + 2) * 64 + lane];
      const s16x8 v3 = lv8[(it * 4 + 3) * 64 + lane];
      accA[0] = __builtin_amdgcn_mfma_f32_16x16x32_bf16(paA, v0, accA[0], 0, 0, 0);
      accA[1] = __builtin_amdgcn_mfma_f32_16x16x32_bf16(paA, v1, accA[1], 0, 0, 0);
      accA[2] = __builtin_amdgcn_mfma_f32_16x16x32_bf16(paA, v2, accA[2], 0, 0, 0);
      accA[3] = __builtin_amdgcn_mfma_f32_16x16x32_bf16(paA, v3, accA[3], 0, 0, 0);
      accB[0] = __builtin_amdgcn_mfma_f32_16x16x32_bf16(paB, v0, accB[0], 0, 0, 0);
      accB[1] = __builtin_amdgcn_mfma_f32_16x16x32_bf16(paB, v1, accB[1], 0, 0, 0);
      accB[2] = __builtin_amdgcn_mfma_f32_16x16x32_bf16(paB, v2, accB[2], 0, 0, 0);
      accB[3] = __builtin_amdgcn_mfma_f32_16x16x32_bf16(paB, v3, accB[3], 0, 0, 0);
      accdA = __builtin_amdgcn_mfma_f32_16x16x32_bf16(paA, onesB, accdA, 0, 0, 0);
      accdB = __builtin_amdgcn_mfma_f32_16x16x32_bf16(paB, onesB, accdB, 0, 0, 0);
    }
    __syncthreads();
  }

  // Merge it-group partials: waves ig=1 dump, waves ig=0 add. Interleaved
  // layout red[r][jw*64+lane] -> conflict-free ds writes/reads.
  const int rbase = jw * 64 + lane;
  if (ig == 1) {
#pragma unroll
    for (int r = 0; r < 4; ++r) {
      red[r * 128 + rbase] = accA[r];
      red[(4 + r) * 128 + rbase] = accB[r];
    }
    red[8 * 128 + rbase] = accdA;
    red[9 * 128 + rbase] = accdB;
  }
  __syncthreads();
  if (ig == 0) {
#pragma unroll
    for (int r = 0; r < 4; ++r) {
      accA[r] += red[r * 128 + rbase];
      accB[r] += red[(4 + r) * 128 + rbase];
    }
    accdA += red[8 * 128 + rbase];
    accdB += red[9 * 128 + rbase];

    const size_t icb = (size_t)ic * NB + b;
    fp32x4* nw = (fp32x4*)numws;
    const int jg = lane >> 4;   // j-group within tile (4 j's per lane)
#pragma unroll
    for (int ct = 0; ct < 4; ++ct) {
      const int c = ct * 16 + l15;
      nw[(icb * 64 + c) * 2304 + jt0 * 4 + jg] = accA[ct];
      nw[(icb * 64 + c) * 2304 + jt1 * 4 + jg] = accB[ct];
    }
    if (l15 == 0) {
      fp32x4* dw = (fp32x4*)denws;
      dw[icb * 2304 + jt0 * 4 + jg] = accdA;
      dw[icb * 2304 + jt1 * 4 + jg] = accdB;
    }
  }
}

// ---------------- Stage 3: combine i-splits, normalize, add residual.
// Fully coalesced float4 streaming thanks to the [icb][c][j] numerator layout.
__global__ __launch_bounds__(256) void combine_kernel(
    const float* __restrict__ bev, const float* __restrict__ numws,
    const float* __restrict__ denws, float* __restrict__ out, int nic)
{
  const int t = blockIdx.x * 256 + threadIdx.x;   // 0..147455 per batch
  const int b = blockIdx.y;
  const int c = t / 2304, j4 = t % 2304;
  const fp32x4* nw = (const fp32x4*)numws;
  const fp32x4* dw = (const fp32x4*)denws;
  fp32x4 n = {0.f, 0.f, 0.f, 0.f}, d = {0.f, 0.f, 0.f, 0.f};
  for (int ic = 0; ic < nic; ++ic) {
    const size_t icb = (size_t)ic * NB + b;
    n += nw[(icb * 64 + c) * 2304 + j4];
    d += dw[icb * 2304 + j4];
  }
  const size_t o4 = ((size_t)b * 64 + c) * 2304 + j4;
  const fp32x4 r = ((const fp32x4*)bev)[o4];
  fp32x4 z;
  z[0] = r[0] + n[0] / d[0];
  z[1] = r[1] + n[1] / d[1];
  z[2] = r[2] + n[2] / d[2];
  z[3] = r[3] + n[3] / d[3];
  ((fp32x4*)out)[o4] = z;
}

extern "C" void kernel_launch(void* const* d_in, const int* in_sizes, int n_in,
                              void* d_out, int out_size, void* d_ws, size_t ws_size,
                              hipStream_t stream) {
  const float* rv  = (const float*)d_in[0];
  const float* bev = (const float*)d_in[1];
  const float* Wq  = (const float*)d_in[2];
  const float* bq  = (const float*)d_in[3];
  const float* Wk  = (const float*)d_in[4];
  const float* bk  = (const float*)d_in[5];
  const float* Wv  = (const float*)d_in[6];
  const float* bv  = (const float*)d_in[7];
  float* out = (float*)d_out;

  short* qbf = (short*)d_ws;
  short* kbf = qbf + (size_t)NB * NPIX * 8;
  short* vbf = kbf + (size_t)NB * NPIX * 8;
  float* denws = (float*)(vbf + (size_t)NB * NPIX * 64);

  const size_t fixed = (size_t)NB * NPIX * (8 + 8 + 64) * 2;  // qkv bytes
  int nic = 4;
  while (nic > 1) {
    size_t need = fixed + (size_t)nic * NB * NPIX * 4            // denws
                        + (size_t)nic * NB * NC * NPIX * 4;      // numws
    if (need <= ws_size) break;
    nic >>= 1;
  }
  float* numws = denws + (size_t)nic * NB * NPIX;

  cvt_qkv_kernel<<<dim3(JQ, NB), 256, 0, stream>>>(
      rv, bev, Wq, bq, Wk, bk, Wv, bv, qbf, kbf, vbf);
  attn_kernel<<<dim3(nic * NB * JQ), 256, 0, stream>>>(
      qbf, kbf, vbf, numws, denws, nic);
  combine_kernel<<<dim3(576, NB), 256, 0, stream>>>(
      bev, numws, denws, out, nic);
}

// Round 4
// 78.804 us; speedup vs baseline: 1.6448x; 1.0397x over previous
//
#include <hip/hip_runtime.h>
#include <hip/hip_bf16.h>

#define NPIX 9216      // H*W
#define NB 2
#define NC 64
#define NJT 576        // NPIX/16  (16-j tiles per (b,ic))
#define JQ 144         // NPIX/64  (64-j blocks)
#define STAGE_I 128    // i's staged in LDS per chunk

typedef __attribute__((ext_vector_type(8))) short s16x8;
typedef __attribute__((ext_vector_type(4))) float fp32x4;

#define LOG2E 1.44269504088896340736f

#if defined(__has_builtin)
#if __has_builtin(__builtin_amdgcn_exp2f)
#define EXP2(x) __builtin_amdgcn_exp2f(x)
#endif
#endif
#ifndef EXP2
#define EXP2(x) exp2f(x)
#endif

__device__ __forceinline__ short bf16b(float f) {
  unsigned u = __builtin_bit_cast(unsigned, f);
  u += 0x7FFFu + ((u >> 16) & 1u);          // RNE, no NaN in this data
  return (short)(u >> 16);
}

__device__ __forceinline__ int cvtpk(float a, float b) {
  int r;
  asm("v_cvt_pk_bf16_f32 %0, %1, %2" : "=v"(r) : "v"(a), "v"(b));
  return r;
}

// ---------------- Stage 1: per-pixel 1x1 convs -> q (pre-scaled by log2e), k
// (bf16 [b][pix][8]) and V packed for the PV-MFMA B-operand:
// vbf[b][blk=i/32][ct=c/16][lane=c%16+16*s][t], i0 = 4s+t (t<4), 16+4s+(t-4).
// Block = 512 threads = 64 j x 8 channel-groups (8 out-ch each).
__global__ __launch_bounds__(512) void cvt_qkv_kernel(
    const float* __restrict__ rv, const float* __restrict__ bev,
    const float* __restrict__ Wq, const float* __restrict__ bq,
    const float* __restrict__ Wk, const float* __restrict__ bk,
    const float* __restrict__ Wv, const float* __restrict__ bv,
    short* __restrict__ qbf, short* __restrict__ kbf, short* __restrict__ vbf)
{
  __shared__ float wlds[5120];       // Wv [64][64] @0, Wq*log2e [8][64] @4096, Wk [8][64] @4608
  __shared__ short vlds[64][72];     // v transpose buffer [c][j] (+pad)
  const int tid = threadIdx.x;
  const int jb = blockIdx.x, b = blockIdx.y;
  const int jbase = jb * 64;

  for (int idx = tid; idx < 5120; idx += 512)
    wlds[idx] = (idx < 4096) ? Wv[idx]
              : (idx < 4608) ? Wq[idx - 4096] * LOG2E
                             : Wk[idx - 4608];
  __syncthreads();

  const int jl = tid & 63, cg = tid >> 6;   // cg 0..7
  const float* xr = rv  + (size_t)b * NC * NPIX + jbase + jl;
  const float* xb = bev + (size_t)b * NC * NPIX + jbase + jl;

  float va[8];
#pragma unroll
  for (int u = 0; u < 8; ++u) va[u] = bv[cg * 8 + u];
  float qk[8];
  if (cg == 0) {
#pragma unroll
    for (int u = 0; u < 8; ++u) qk[u] = bq[u] * LOG2E;
  } else if (cg == 1) {
#pragma unroll
    for (int u = 0; u < 8; ++u) qk[u] = bk[u];
  }

  for (int c2 = 0; c2 < 32; ++c2) {
    const int c = c2 * 2;
    const float x0 = xr[(size_t)c * NPIX], x1 = xr[(size_t)(c + 1) * NPIX];
#pragma unroll
    for (int u = 0; u < 8; ++u) {
      float2 w = *(const float2*)&wlds[(cg * 8 + u) * 64 + c];
      va[u] = fmaf(w.y, x1, fmaf(w.x, x0, va[u]));
    }
    if (cg == 0) {
      const float y0 = xb[(size_t)c * NPIX], y1 = xb[(size_t)(c + 1) * NPIX];
#pragma unroll
      for (int u = 0; u < 8; ++u) {
        float2 w = *(const float2*)&wlds[4096 + u * 64 + c];
        qk[u] = fmaf(w.y, y1, fmaf(w.x, y0, qk[u]));
      }
    } else if (cg == 1) {
#pragma unroll
      for (int u = 0; u < 8; ++u) {
        float2 w = *(const float2*)&wlds[4608 + u * 64 + c];
        qk[u] = fmaf(w.y, x1, fmaf(w.x, x0, qk[u]));
      }
    }
  }

  if (cg == 0) {
    s16x8 qp;
#pragma unroll
    for (int u = 0; u < 8; ++u) qp[u] = bf16b(qk[u]);
    ((s16x8*)qbf)[(size_t)b * NPIX + jbase + jl] = qp;
  } else if (cg == 1) {
    s16x8 kp;
#pragma unroll
    for (int u = 0; u < 8; ++u) kp[u] = bf16b(qk[u]);
    ((s16x8*)kbf)[(size_t)b * NPIX + jbase + jl] = kp;
  }
#pragma unroll
  for (int u = 0; u < 8; ++u) vlds[cg * 8 + u][jl] = bf16b(va[u]);
  __syncthreads();

  s16x8* vout = (s16x8*)vbf + ((size_t)b * 288 + jb * 2) * 256;
  const int vecidx = tid;                   // 0..511
  const int r = vecidx >> 8, ct = (vecidx >> 6) & 3, ln = vecidx & 63;
  const int s = ln >> 4, cc = ct * 16 + (ln & 15);
  s16x8 vv;
#pragma unroll
  for (int t = 0; t < 8; ++t) {
    const int i0 = (t < 4) ? (4 * s + t) : (12 + 4 * s + t);
    vv[t] = vlds[cc][r * 32 + i0];
  }
  vout[vecidx] = vv;
}

// ---------------- Stage 2: flash attention. Block = 256 threads = 4 waves over
// 64 j's: wave = (ig = wid>>1, jw = wid&1); ig splits the 128-i chunk in half.
// Double-buffered LDS staging (reg-staged): loads for chunk ch+2 issue before
// compute of chunk ch; ds_writes of ch+1 land right after the single barrier.
// numws layout: [icb][c][NPIX] (float), denws: [icb][NPIX] -> coalesced combine.
__global__ __launch_bounds__(256, 4) void attn_kernel(
    const short* __restrict__ qbf, const short* __restrict__ kbf,
    const short* __restrict__ vbf,
    float* __restrict__ numws, float* __restrict__ denws, int nic)
{
  __shared__ __align__(16) char smem[36896];
  s16x8* lv = (s16x8*)smem;                 // [2][1024] 32 KB V double-buffer
  s16x8* lq = (s16x8*)(smem + 32768);       // [2][129]; slot 128 = zeros
  fp32x4* red = (fp32x4*)smem;              // [10][128] aliases lv after loop

  const int bid = blockIdx.x;
  const int jq = bid % JQ;
  const int rest = bid / JQ;
  const int b = rest % NB;
  const int ic = rest / NB;
  const int tid = threadIdx.x;        // 0..255
  const int wid = tid >> 6, lane = tid & 63, l15 = lane & 15;
  const int jw = wid & 1;             // which j-pair of the block's 64 j
  const int ig = wid >> 1;            // it-group: 0 -> it 0,1 ; 1 -> it 2,3
  const int jt0 = jq * 4 + jw * 2, jt1 = jt0 + 1;
  const int ichunk = NPIX / nic;
  const int ibase = ic * ichunk;
  const int nchunks = ichunk / STAGE_I;     // >= 18

  const s16x8* q8 = (const s16x8*)qbf + (size_t)b * NPIX;
  const s16x8* k8 = (const s16x8*)kbf + (size_t)b * NPIX;
  const s16x8* v8 = (const s16x8*)vbf;

  const s16x8 zS = {0, 0, 0, 0, 0, 0, 0, 0};
  const fp32x4 z4 = {0.f, 0.f, 0.f, 0.f};

  s16x8 kf0 = zS, kf1 = zS, onesB = zS;
  if (lane < 16) {
    kf0 = k8[jt0 * 16 + lane];
    kf1 = k8[jt1 * 16 + lane];
  }
  if (l15 == 0) {
    const short one = 0x3F80;  // bf16 1.0
#pragma unroll
    for (int t = 0; t < 8; ++t) onesB[t] = one;
  }

  fp32x4 accA[4] = {z4, z4, z4, z4}, accB[4] = {z4, z4, z4, z4};
  fp32x4 accdA = z4, accdB = z4;

  s16x8 vreg[4], qreg;
  auto loadregs = [&](int ch) {
    const int cbase = ibase + ch * STAGE_I;
    const size_t vsrc = ((size_t)b * 288 + (cbase >> 5)) * 256;
#pragma unroll
    for (int r = 0; r < 4; ++r) vreg[r] = v8[vsrc + r * 256 + tid];
    if (tid < 128) qreg = q8[cbase + tid];
  };
  auto writeLDS = [&](int bufi) {
    s16x8* lvb = lv + bufi * 1024;
#pragma unroll
    for (int r = 0; r < 4; ++r) lvb[r * 256 + tid] = vreg[r];
    if (tid < 128) lq[bufi * 129 + tid] = qreg;
  };

  if (tid < 2) lq[tid * 129 + 128] = zS;    // shared zero A-rows slot per buffer
  loadregs(0);
  writeLDS(0);
  loadregs(1);
  int cur = 0;

  for (int ch = 0; ch < nchunks; ++ch) {
    __syncthreads();                        // buf[cur] visible; prev reads done
    if (ch + 1 < nchunks) writeLDS(cur ^ 1);
    if (ch + 2 < nchunks) loadregs(ch + 2);
    const s16x8* lvb = lv + cur * 1024;
    const s16x8* lqb = lq + cur * 129;
#pragma unroll
    for (int itl = 0; itl < 2; ++itl) {
      const int it = ig * 2 + itl;
      int qi0 = it * 32 + l15, qi1 = qi0 + 16;
      if (lane >= 16) { qi0 = 128; qi1 = 128; }
      const s16x8 q0 = lqb[qi0], q1 = lqb[qi1];
      const fp32x4 sA0 = __builtin_amdgcn_mfma_f32_16x16x32_bf16(q0, kf0, z4, 0, 0, 0);
      const fp32x4 sA1 = __builtin_amdgcn_mfma_f32_16x16x32_bf16(q1, kf0, z4, 0, 0, 0);
      const fp32x4 sB0 = __builtin_amdgcn_mfma_f32_16x16x32_bf16(q0, kf1, z4, 0, 0, 0);
      const fp32x4 sB1 = __builtin_amdgcn_mfma_f32_16x16x32_bf16(q1, kf1, z4, 0, 0, 0);
      int4 piA, piB;
      piA.x = cvtpk(EXP2(sA0[0]), EXP2(sA0[1]));
      piA.y = cvtpk(EXP2(sA0[2]), EXP2(sA0[3]));
      piA.z = cvtpk(EXP2(sA1[0]), EXP2(sA1[1]));
      piA.w = cvtpk(EXP2(sA1[2]), EXP2(sA1[3]));
      piB.x = cvtpk(EXP2(sB0[0]), EXP2(sB0[1]));
      piB.y = cvtpk(EXP2(sB0[2]), EXP2(sB0[3]));
      piB.z = cvtpk(EXP2(sB1[0]), EXP2(sB1[1]));
      piB.w = cvtpk(EXP2(sB1[2]), EXP2(sB1[3]));
      const s16x8 paA = __builtin_bit_cast(s16x8, piA);
      const s16x8 paB = __builtin_bit_cast(s16x8, piB);
      const s16x8 v0 = lvb[(it * 4 + 0) * 64 + lane];
      const s16x8 v1 = lvb[(it * 4 + 1) * 64 + lane];
      const s16x8 v2 = lvb[(it * 4 + 2) * 64 + lane];
      const s16x8 v3 = lvb[(it * 4 + 3) * 64 + lane];
      accA[0] = __builtin_amdgcn_mfma_f32_16x16x32_bf16(paA, v0, accA[0], 0, 0, 0);
      accA[1] = __builtin_amdgcn_mfma_f32_16x16x32_bf16(paA, v1, accA[1], 0, 0, 0);
      accA[2] = __builtin_amdgcn_mfma_f32_16x16x32_bf16(paA, v2, accA[2], 0, 0, 0);
      accA[3] = __builtin_amdgcn_mfma_f32_16x16x32_bf16(paA, v3, accA[3], 0, 0, 0);
      accB[0] = __builtin_amdgcn_mfma_f32_16x16x32_bf16(paB, v0, accB[0], 0, 0, 0);
      accB[1] = __builtin_amdgcn_mfma_f32_16x16x32_bf16(paB, v1, accB[1], 0, 0, 0);
      accB[2] = __builtin_amdgcn_mfma_f32_16x16x32_bf16(paB, v2, accB[2], 0, 0, 0);
      accB[3] = __builtin_amdgcn_mfma_f32_16x16x32_bf16(paB, v3, accB[3], 0, 0, 0);
      accdA = __builtin_amdgcn_mfma_f32_16x16x32_bf16(paA, onesB, accdA, 0, 0, 0);
      accdB = __builtin_amdgcn_mfma_f32_16x16x32_bf16(paB, onesB, accdB, 0, 0, 0);
    }
    cur ^= 1;
  }
  __syncthreads();

  // Merge it-group partials: waves ig=1 dump, waves ig=0 add.
  const int rbase = jw * 64 + lane;
  if (ig == 1) {
#pragma unroll
    for (int r = 0; r < 4; ++r) {
      red[r * 128 + rbase] = accA[r];
      red[(4 + r) * 128 + rbase] = accB[r];
    }
    red[8 * 128 + rbase] = accdA;
    red[9 * 128 + rbase] = accdB;
  }
  __syncthreads();
  if (ig == 0) {
#pragma unroll
    for (int r = 0; r < 4; ++r) {
      accA[r] += red[r * 128 + rbase];
      accB[r] += red[(4 + r) * 128 + rbase];
    }
    accdA += red[8 * 128 + rbase];
    accdB += red[9 * 128 + rbase];

    const size_t icb = (size_t)ic * NB + b;
    fp32x4* nw = (fp32x4*)numws;
    const int jg = lane >> 4;   // j-group within tile (4 j's per lane)
#pragma unroll
    for (int ct = 0; ct < 4; ++ct) {
      const int c = ct * 16 + l15;
      nw[(icb * 64 + c) * 2304 + jt0 * 4 + jg] = accA[ct];
      nw[(icb * 64 + c) * 2304 + jt1 * 4 + jg] = accB[ct];
    }
    if (l15 == 0) {
      fp32x4* dw = (fp32x4*)denws;
      dw[icb * 2304 + jt0 * 4 + jg] = accdA;
      dw[icb * 2304 + jt1 * 4 + jg] = accdB;
    }
  }
}

// ---------------- Stage 3: combine i-splits, normalize, add residual.
__global__ __launch_bounds__(256) void combine_kernel(
    const float* __restrict__ bev, const float* __restrict__ numws,
    const float* __restrict__ denws, float* __restrict__ out, int nic)
{
  const int t = blockIdx.x * 256 + threadIdx.x;   // 0..147455 per batch
  const int b = blockIdx.y;
  const int c = t / 2304, j4 = t % 2304;
  const fp32x4* nw = (const fp32x4*)numws;
  const fp32x4* dw = (const fp32x4*)denws;
  fp32x4 n = {0.f, 0.f, 0.f, 0.f}, d = {0.f, 0.f, 0.f, 0.f};
  for (int ic = 0; ic < nic; ++ic) {
    const size_t icb = (size_t)ic * NB + b;
    n += nw[(icb * 64 + c) * 2304 + j4];
    d += dw[icb * 2304 + j4];
  }
  const size_t o4 = ((size_t)b * 64 + c) * 2304 + j4;
  const fp32x4 r = ((const fp32x4*)bev)[o4];
  fp32x4 z;
  z[0] = r[0] + n[0] / d[0];
  z[1] = r[1] + n[1] / d[1];
  z[2] = r[2] + n[2] / d[2];
  z[3] = r[3] + n[3] / d[3];
  ((fp32x4*)out)[o4] = z;
}

extern "C" void kernel_launch(void* const* d_in, const int* in_sizes, int n_in,
                              void* d_out, int out_size, void* d_ws, size_t ws_size,
                              hipStream_t stream) {
  const float* rv  = (const float*)d_in[0];
  const float* bev = (const float*)d_in[1];
  const float* Wq  = (const float*)d_in[2];
  const float* bq  = (const float*)d_in[3];
  const float* Wk  = (const float*)d_in[4];
  const float* bk  = (const float*)d_in[5];
  const float* Wv  = (const float*)d_in[6];
  const float* bv  = (const float*)d_in[7];
  float* out = (float*)d_out;

  short* qbf = (short*)d_ws;
  short* kbf = qbf + (size_t)NB * NPIX * 8;
  short* vbf = kbf + (size_t)NB * NPIX * 8;
  float* denws = (float*)(vbf + (size_t)NB * NPIX * 64);

  const size_t fixed = (size_t)NB * NPIX * (8 + 8 + 64) * 2;  // qkv bytes
  int nic = 4;
  while (nic > 1) {
    size_t need = fixed + (size_t)nic * NB * NPIX * 4            // denws
                        + (size_t)nic * NB * NC * NPIX * 4;      // numws
    if (need <= ws_size) break;
    nic >>= 1;
  }
  float* numws = denws + (size_t)nic * NB * NPIX;

  cvt_qkv_kernel<<<dim3(JQ, NB), 512, 0, stream>>>(
      rv, bev, Wq, bq, Wk, bk, Wv, bv, qbf, kbf, vbf);
  attn_kernel<<<dim3(nic * NB * JQ), 256, 0, stream>>>(
      qbf, kbf, vbf, numws, denws, nic);
  combine_kernel<<<dim3(576, NB), 256, 0, stream>>>(
      bev, numws, denws, out, nic);
}